// Round 2
// baseline (7842.180 us; speedup 1.0000x reference)
//
#include <hip/hip_runtime.h>

#define H 128
#define RT 4   // rows (edges/nodes) per wave-iteration
#define KC 8   // k-chunk size (register double-buffered)

__device__ __forceinline__ float f4get(const float4& v, int i) {
    return i == 0 ? v.x : i == 1 ? v.y : i == 2 ? v.z : v.w;
}

// ---------------------------------------------------------------------------
// Node projection: P[y][n][:] = NF[n] @ W_y  (+ b if y==1)
// ---------------------------------------------------------------------------
__global__ __launch_bounds__(512, 4)
void node_proj_kernel(const float* __restrict__ nf, const float* __restrict__ W,
                      const float* __restrict__ b, float* __restrict__ P,
                      int n_nodes) {
    __shared__ float Wlds[H * H];  // 64 KB
    const int y = blockIdx.y;
    {
        const float* Wsrc = W + (size_t)y * H * H;
        for (int i = threadIdx.x; i < H * H / 4; i += blockDim.x)
            ((float4*)Wlds)[i] = ((const float4*)Wsrc)[i];
    }
    __syncthreads();

    const int lane = threadIdx.x & 63;
    const int wv = __builtin_amdgcn_readfirstlane(threadIdx.x >> 6);
    const int wpb = blockDim.x >> 6;
    const int wid = blockIdx.x * wpb + wv;
    const int nwaves = gridDim.x * wpb;
    const int ntiles = (n_nodes + RT - 1) / RT;
    const int c2 = lane * 2;
    float* Pout = P + (size_t)y * n_nodes * H;
    float2 bias = make_float2(0.f, 0.f);
    if (y == 1) bias = *(const float2*)&b[c2];

    for (int t = wid; t < ntiles; t += nwaves) {
        const int row0 = t * RT;
        const float* rp[RT];
#pragma unroll
        for (int r = 0; r < RT; ++r) {
            int rr = row0 + r;
            if (rr >= n_nodes) rr = n_nodes - 1;
            rp[r] = nf + (size_t)rr * H;
        }

        float2 acc[RT];
#pragma unroll
        for (int r = 0; r < RT; ++r) acc[r] = make_float2(0.f, 0.f);

        float4 ea[2][RT], eb[2][RT];
#pragma unroll
        for (int r = 0; r < RT; ++r) {
            ea[0][r] = *(const float4*)(rp[r] + 0);
            eb[0][r] = *(const float4*)(rp[r] + 4);
        }
#pragma unroll
        for (int c = 0; c < H / KC; ++c) {
            const int cur = c & 1, nxt = cur ^ 1;
            if (c + 1 < H / KC) {
#pragma unroll
                for (int r = 0; r < RT; ++r) {
                    ea[nxt][r] = *(const float4*)(rp[r] + (c + 1) * KC);
                    eb[nxt][r] = *(const float4*)(rp[r] + (c + 1) * KC + 4);
                }
            }
#pragma unroll
            for (int kk = 0; kk < KC; ++kk) {
                const int k = c * KC + kk;
                float2 w2 = *(const float2*)&Wlds[k * H + c2];
#pragma unroll
                for (int r = 0; r < RT; ++r) {
                    float x = kk < 4 ? f4get(ea[cur][r], kk) : f4get(eb[cur][r], kk - 4);
                    acc[r].x = fmaf(x, w2.x, acc[r].x);
                    acc[r].y = fmaf(x, w2.y, acc[r].y);
                }
            }
        }

#pragma unroll
        for (int r = 0; r < RT; ++r) {
            int rr = row0 + r;
            if (rr < n_nodes) {
                float2 v;
                v.x = acc[r].x + bias.x;
                v.y = acc[r].y + bias.y;
                *(float2*)&Pout[(size_t)rr * H + c2] = v;
            }
        }
    }
}

// ---------------------------------------------------------------------------
// Edge kernel: m = relu(P1[s] + P2[r] + EF[e] @ W3); atomicAdd into out[r]
// Register-pipelined EF chunks; P rows prefetched at tile start.
// ---------------------------------------------------------------------------
__global__ __launch_bounds__(512, 4)
void edge_kernel(const float* __restrict__ ef, const int* __restrict__ senders,
                 const int* __restrict__ receivers, const float* __restrict__ W,
                 const float* __restrict__ P, float* __restrict__ out,
                 int n_edges, int n_nodes) {
    __shared__ float Wlds[H * H];  // 64 KB: W3
    {
        const float* Wsrc = W + (size_t)2 * H * H;
        for (int i = threadIdx.x; i < H * H / 4; i += blockDim.x)
            ((float4*)Wlds)[i] = ((const float4*)Wsrc)[i];
    }
    __syncthreads();

    const int lane = threadIdx.x & 63;
    const int wv = __builtin_amdgcn_readfirstlane(threadIdx.x >> 6);
    const int wpb = blockDim.x >> 6;
    const int wid = blockIdx.x * wpb + wv;
    const int nwaves = gridDim.x * wpb;
    const int ntiles = (n_edges + RT - 1) / RT;
    const float* __restrict__ P1 = P;
    const float* __restrict__ P2 = P + (size_t)n_nodes * H;
    const int c2 = lane * 2;

    for (int t = wid; t < ntiles; t += nwaves) {
        const int row0 = t * RT;
        int se[RT], re[RT];
        const float* efp[RT];
#pragma unroll
        for (int r = 0; r < RT; ++r) {
            int e = row0 + r;
            if (e >= n_edges) e = n_edges - 1;
            se[r] = senders[e];
            re[r] = receivers[e];
            efp[r] = ef + (size_t)e * H;
        }
        // prefetch P rows early — latency hides under the k-loop
        float2 p1v[RT], p2v[RT];
#pragma unroll
        for (int r = 0; r < RT; ++r) {
            p1v[r] = *(const float2*)&P1[(size_t)se[r] * H + c2];
            p2v[r] = *(const float2*)&P2[(size_t)re[r] * H + c2];
        }

        float2 acc[RT];
#pragma unroll
        for (int r = 0; r < RT; ++r) acc[r] = make_float2(0.f, 0.f);

        float4 ea[2][RT], eb[2][RT];
#pragma unroll
        for (int r = 0; r < RT; ++r) {
            ea[0][r] = *(const float4*)(efp[r] + 0);
            eb[0][r] = *(const float4*)(efp[r] + 4);
        }
#pragma unroll
        for (int c = 0; c < H / KC; ++c) {
            const int cur = c & 1, nxt = cur ^ 1;
            if (c + 1 < H / KC) {
#pragma unroll
                for (int r = 0; r < RT; ++r) {
                    ea[nxt][r] = *(const float4*)(efp[r] + (c + 1) * KC);
                    eb[nxt][r] = *(const float4*)(efp[r] + (c + 1) * KC + 4);
                }
            }
#pragma unroll
            for (int kk = 0; kk < KC; ++kk) {
                const int k = c * KC + kk;
                float2 w2 = *(const float2*)&Wlds[k * H + c2];
#pragma unroll
                for (int r = 0; r < RT; ++r) {
                    float x = kk < 4 ? f4get(ea[cur][r], kk) : f4get(eb[cur][r], kk - 4);
                    acc[r].x = fmaf(x, w2.x, acc[r].x);
                    acc[r].y = fmaf(x, w2.y, acc[r].y);
                }
            }
        }

#pragma unroll
        for (int r = 0; r < RT; ++r) {
            int e = row0 + r;
            if (e < n_edges) {
                float mx = fmaxf(acc[r].x + p1v[r].x + p2v[r].x, 0.f);
                float my = fmaxf(acc[r].y + p1v[r].y + p2v[r].y, 0.f);
                float* dst = out + (size_t)re[r] * H + c2;
                atomicAdd(dst + 0, mx);
                atomicAdd(dst + 1, my);
            }
        }
    }
}

// ---------------------------------------------------------------------------
// LayerNorm(nf + aggr) in-place on out
// ---------------------------------------------------------------------------
__global__ __launch_bounds__(256, 4)
void ln_kernel(const float* __restrict__ nf, const float* __restrict__ lnw,
               const float* __restrict__ lnb, float* __restrict__ out, int n_nodes) {
    const int wv = threadIdx.x >> 6;
    const int lane = threadIdx.x & 63;
    const int row = blockIdx.x * (blockDim.x >> 6) + wv;
    if (row >= n_nodes) return;
    float2 a = ((const float2*)(nf + (size_t)row * H))[lane];
    float2 g = ((float2*)(out + (size_t)row * H))[lane];
    float vx = a.x + g.x, vy = a.y + g.y;

    float s = vx + vy;
#pragma unroll
    for (int m = 32; m; m >>= 1) s += __shfl_xor(s, m, 64);
    float mu = s * (1.f / H);
    float dx = vx - mu, dy = vy - mu;
    float q = dx * dx + dy * dy;
#pragma unroll
    for (int m = 32; m; m >>= 1) q += __shfl_xor(q, m, 64);
    float rs = rsqrtf(q * (1.f / H) + 1e-5f);

    float2 w2 = ((const float2*)lnw)[lane];
    float2 b2 = ((const float2*)lnb)[lane];
    float2 o;
    o.x = dx * rs * w2.x + b2.x;
    o.y = dy * rs * w2.y + b2.y;
    ((float2*)(out + (size_t)row * H))[lane] = o;
}

// ---------------------------------------------------------------------------
// Fallback (workspace too small): fully naive edge pass
// ---------------------------------------------------------------------------
__global__ void naive_edge_kernel(const float* __restrict__ nf, const int* __restrict__ s,
                                  const int* __restrict__ r, const float* __restrict__ ef,
                                  const float* __restrict__ W, const float* __restrict__ b,
                                  float* __restrict__ out, int n_edges) {
    int e = blockIdx.x * 2 + (threadIdx.x >> 7);
    int c = threadIdx.x & 127;
    if (e >= n_edges) return;
    int se = s[e], re = r[e];
    float acc = b[c];
    for (int k = 0; k < H; ++k) {
        acc += nf[(size_t)se * H + k] * W[(size_t)k * H + c];
        acc += nf[(size_t)re * H + k] * W[(size_t)(H + k) * H + c];
        acc += ef[(size_t)e * H + k] * W[(size_t)(2 * H + k) * H + c];
    }
    atomicAdd(&out[(size_t)re * H + c], fmaxf(acc, 0.f));
}

// ---------------------------------------------------------------------------
extern "C" void kernel_launch(void* const* d_in, const int* in_sizes, int n_in,
                              void* d_out, int out_size, void* d_ws, size_t ws_size,
                              hipStream_t stream) {
    const float* nf        = (const float*)d_in[0];
    const int*   senders   = (const int*)d_in[1];
    const int*   receivers = (const int*)d_in[2];
    const float* ef        = (const float*)d_in[3];
    const float* W         = (const float*)d_in[4];
    const float* b         = (const float*)d_in[5];
    const float* lnw       = (const float*)d_in[6];
    const float* lnb       = (const float*)d_in[7];
    float* out = (float*)d_out;

    const int n_nodes = in_sizes[0] / H;  // 50000
    const int n_edges = in_sizes[1];      // 800000

    hipMemsetAsync(d_out, 0, (size_t)n_nodes * H * sizeof(float), stream);

    const size_t need = (size_t)2 * n_nodes * H * sizeof(float);
    if (ws_size >= need) {
        float* P = (float*)d_ws;
        node_proj_kernel<<<dim3(256, 2), 512, 0, stream>>>(nf, W, b, P, n_nodes);
        edge_kernel<<<512, 512, 0, stream>>>(ef, senders, receivers, W, P, out,
                                             n_edges, n_nodes);
    } else {
        naive_edge_kernel<<<(n_edges + 1) / 2, 256, 0, stream>>>(
            nf, senders, receivers, ef, W, b, out, n_edges);
    }

    ln_kernel<<<(n_nodes + 3) / 4, 256, 0, stream>>>(nf, lnw, lnb, out, n_nodes);
}

// Round 3
// 631.204 us; speedup vs baseline: 12.4242x; 12.4242x over previous
//
#include <hip/hip_runtime.h>

#define H 128
#define BM 128   // edges per block tile
#define NSRC 3

typedef __bf16 bf16;
typedef __bf16 bf16x8 __attribute__((ext_vector_type(8)));
typedef float f32x4 __attribute__((ext_vector_type(4)));

// ---------------------------------------------------------------------------
// Prep: W [384][128] fp32 -> per-source transposed [c][k] bf16 hi/lo buffers,
// stored PRE-SWIZZLED so GEMM blocks can copy them linearly into LDS.
// byte offset within a 32KB buffer: (c*256 + k*2) ^ ((c&7)<<4)
// ---------------------------------------------------------------------------
__global__ void prep_w_kernel(const float* __restrict__ W, bf16* __restrict__ wbuf) {
    int g = blockIdx.x * blockDim.x + threadIdx.x;
    if (g >= NSRC * H * H) return;
    int src = g >> 14;
    int k = (g >> 7) & 127;
    int c = g & 127;
    float v = W[((size_t)src * H + k) * H + c];
    bf16 hi = (bf16)v;
    bf16 lo = (bf16)(v - (float)hi);
    unsigned off = ((unsigned)(c * 256 + k * 2)) ^ ((unsigned)((c & 7) << 4));
    wbuf[(size_t)(src * 2 + 0) * (H * H) + (off >> 1)] = hi;
    wbuf[(size_t)(src * 2 + 1) * (H * H) + (off >> 1)] = lo;
}

// ---------------------------------------------------------------------------
// Fused edge GEMM: acc[e][c] = sum over 3 sources of X_src[e] @ W_src
// X_0 = NF[senders[e]], X_1 = NF[receivers[e]], X_2 = EF[e]   (K=384 total)
// Split-bf16: X = Xh + Xl, W = Wh + Wl; products XhWh + XlWh + XhWl.
// Epilogue: +bias, relu, atomicAdd into out[receivers[e]].
// ---------------------------------------------------------------------------
__global__ __launch_bounds__(512, 2)
void fused_edge_kernel(const float* __restrict__ nf, const int* __restrict__ senders,
                       const int* __restrict__ receivers, const float* __restrict__ ef,
                       const float* __restrict__ b, const bf16* __restrict__ wbuf,
                       float* __restrict__ out, int n_edges) {
    __shared__ __align__(16) bf16 Alds[2][BM * H];  // hi/lo, 32KB each
    __shared__ __align__(16) bf16 Wlds[2][H * H];   // hi/lo, 32KB each

    const int t = threadIdx.x;
    const int lane = t & 63;
    const int wid = t >> 6;       // 0..7
    const int wm = wid >> 1;      // row group: 32 edges
    const int wn = wid & 1;       // col group: 64 cols
    const int row0 = blockIdx.x * BM;

    f32x4 acc[2][4];
#pragma unroll
    for (int i = 0; i < 2; ++i)
#pragma unroll
        for (int j = 0; j < 4; ++j) acc[i][j] = (f32x4){0.f, 0.f, 0.f, 0.f};

    // staging assignment: thread -> (row = t>>2, k-range = (t&3)*32 .. +32)
    const int srow = t >> 2;
    const int kp = (t & 3) * 32;
    int erow = row0 + srow;
    if (erow >= n_edges) erow = n_edges - 1;
    const int sidx = senders[erow];
    const int ridx = receivers[erow];

    for (int src = 0; src < NSRC; ++src) {
        __syncthreads();  // previous phase's LDS reads done
        // ---- stage W chunk (pre-swizzled in ws -> linear LDS copy) ----
        {
            const int4* g0 = (const int4*)(wbuf + (size_t)(src * 2 + 0) * (H * H));
            const int4* g1 = (const int4*)(wbuf + (size_t)(src * 2 + 1) * (H * H));
            int4* d0 = (int4*)&Wlds[0][0];
            int4* d1 = (int4*)&Wlds[1][0];
#pragma unroll
            for (int i = 0; i < 4; ++i) {
                d0[i * 512 + t] = g0[i * 512 + t];
                d1[i * 512 + t] = g1[i * 512 + t];
            }
        }
        // ---- stage A tile: fp32 -> bf16 hi/lo, swizzled ds_write_b128 ----
        {
            const float* srcrow = (src == 0) ? nf + (size_t)sidx * H
                                : (src == 1) ? nf + (size_t)ridx * H
                                             : ef + (size_t)erow * H;
#pragma unroll
            for (int i = 0; i < 4; ++i) {
                const int k0 = kp + i * 8;
                float4 va = *(const float4*)(srcrow + k0);
                float4 vb = *(const float4*)(srcrow + k0 + 4);
                float vals[8] = {va.x, va.y, va.z, va.w, vb.x, vb.y, vb.z, vb.w};
                bf16x8 hv, lv;
#pragma unroll
                for (int j = 0; j < 8; ++j) {
                    bf16 h = (bf16)vals[j];
                    hv[j] = h;
                    lv[j] = (bf16)(vals[j] - (float)h);
                }
                unsigned off = ((unsigned)(srow * 256 + k0 * 2)) ^ ((unsigned)((srow & 7) << 4));
                *(bf16x8*)((char*)&Alds[0][0] + off) = hv;
                *(bf16x8*)((char*)&Alds[1][0] + off) = lv;
            }
        }
        __syncthreads();
        // ---- 4 k-steps of 32 ----
#pragma unroll
        for (int ks = 0; ks < 4; ++ks) {
            const int kb = ks * 32 + (lane >> 4) * 8;
            bf16x8 ah[2], al[2];
#pragma unroll
            for (int rf = 0; rf < 2; ++rf) {
                const int r = wm * 32 + rf * 16 + (lane & 15);
                unsigned off = ((unsigned)(r * 256 + kb * 2)) ^ ((unsigned)((r & 7) << 4));
                ah[rf] = *(const bf16x8*)((const char*)&Alds[0][0] + off);
                al[rf] = *(const bf16x8*)((const char*)&Alds[1][0] + off);
            }
            bf16x8 bh[4], bl[4];
#pragma unroll
            for (int cf = 0; cf < 4; ++cf) {
                const int c = wn * 64 + cf * 16 + (lane & 15);
                unsigned off = ((unsigned)(c * 256 + kb * 2)) ^ ((unsigned)((c & 7) << 4));
                bh[cf] = *(const bf16x8*)((const char*)&Wlds[0][0] + off);
                bl[cf] = *(const bf16x8*)((const char*)&Wlds[1][0] + off);
            }
#pragma unroll
            for (int rf = 0; rf < 2; ++rf)
#pragma unroll
                for (int cf = 0; cf < 4; ++cf) {
                    acc[rf][cf] = __builtin_amdgcn_mfma_f32_16x16x32_bf16(ah[rf], bh[cf], acc[rf][cf], 0, 0, 0);
                    acc[rf][cf] = __builtin_amdgcn_mfma_f32_16x16x32_bf16(al[rf], bh[cf], acc[rf][cf], 0, 0, 0);
                    acc[rf][cf] = __builtin_amdgcn_mfma_f32_16x16x32_bf16(ah[rf], bl[cf], acc[rf][cf], 0, 0, 0);
                }
        }
    }

    // ---- epilogue: bias + relu + atomic scatter (C/D: col=lane&15, row=(lane>>4)*4+q) ----
#pragma unroll
    for (int rf = 0; rf < 2; ++rf) {
        int rr[4];
        bool ok[4];
#pragma unroll
        for (int q = 0; q < 4; ++q) {
            int e = row0 + wm * 32 + rf * 16 + (lane >> 4) * 4 + q;
            ok[q] = (e < n_edges);
            rr[q] = receivers[ok[q] ? e : (n_edges - 1)];
        }
#pragma unroll
        for (int cf = 0; cf < 4; ++cf) {
            const int col = wn * 64 + cf * 16 + (lane & 15);
            const float bias = b[col];
#pragma unroll
            for (int q = 0; q < 4; ++q) {
                if (ok[q]) {
                    float m = fmaxf(acc[rf][cf][q] + bias, 0.f);
                    atomicAdd(&out[(size_t)rr[q] * H + col], m);
                }
            }
        }
    }
}

// ---------------------------------------------------------------------------
// LayerNorm(nf + aggr) in-place on out
// ---------------------------------------------------------------------------
__global__ __launch_bounds__(256, 4)
void ln_kernel(const float* __restrict__ nf, const float* __restrict__ lnw,
               const float* __restrict__ lnb, float* __restrict__ out, int n_nodes) {
    const int wv = threadIdx.x >> 6;
    const int lane = threadIdx.x & 63;
    const int row = blockIdx.x * (blockDim.x >> 6) + wv;
    if (row >= n_nodes) return;
    float2 a = ((const float2*)(nf + (size_t)row * H))[lane];
    float2 g = ((float2*)(out + (size_t)row * H))[lane];
    float vx = a.x + g.x, vy = a.y + g.y;

    float s = vx + vy;
#pragma unroll
    for (int m = 32; m; m >>= 1) s += __shfl_xor(s, m, 64);
    float mu = s * (1.f / H);
    float dx = vx - mu, dy = vy - mu;
    float q = dx * dx + dy * dy;
#pragma unroll
    for (int m = 32; m; m >>= 1) q += __shfl_xor(q, m, 64);
    float rs = rsqrtf(q * (1.f / H) + 1e-5f);

    float2 w2 = ((const float2*)lnw)[lane];
    float2 b2 = ((const float2*)lnb)[lane];
    float2 o;
    o.x = dx * rs * w2.x + b2.x;
    o.y = dy * rs * w2.y + b2.y;
    ((float2*)(out + (size_t)row * H))[lane] = o;
}

// ---------------------------------------------------------------------------
// Fallback (workspace too small): fully naive edge pass
// ---------------------------------------------------------------------------
__global__ void naive_edge_kernel(const float* __restrict__ nf, const int* __restrict__ s,
                                  const int* __restrict__ r, const float* __restrict__ ef,
                                  const float* __restrict__ W, const float* __restrict__ b,
                                  float* __restrict__ out, int n_edges) {
    int e = blockIdx.x * 2 + (threadIdx.x >> 7);
    int c = threadIdx.x & 127;
    if (e >= n_edges) return;
    int se = s[e], re = r[e];
    float acc = b[c];
    for (int k = 0; k < H; ++k) {
        acc += nf[(size_t)se * H + k] * W[(size_t)k * H + c];
        acc += nf[(size_t)re * H + k] * W[(size_t)(H + k) * H + c];
        acc += ef[(size_t)e * H + k] * W[(size_t)(2 * H + k) * H + c];
    }
    atomicAdd(&out[(size_t)re * H + c], fmaxf(acc, 0.f));
}

// ---------------------------------------------------------------------------
extern "C" void kernel_launch(void* const* d_in, const int* in_sizes, int n_in,
                              void* d_out, int out_size, void* d_ws, size_t ws_size,
                              hipStream_t stream) {
    const float* nf        = (const float*)d_in[0];
    const int*   senders   = (const int*)d_in[1];
    const int*   receivers = (const int*)d_in[2];
    const float* ef        = (const float*)d_in[3];
    const float* W         = (const float*)d_in[4];
    const float* b         = (const float*)d_in[5];
    const float* lnw       = (const float*)d_in[6];
    const float* lnb       = (const float*)d_in[7];
    float* out = (float*)d_out;

    const int n_nodes = in_sizes[0] / H;  // 50000
    const int n_edges = in_sizes[1];      // 800000

    hipMemsetAsync(d_out, 0, (size_t)n_nodes * H * sizeof(float), stream);

    const size_t need = (size_t)NSRC * 2 * H * H * sizeof(bf16);  // 192 KB
    if (ws_size >= need) {
        bf16* wbuf = (bf16*)d_ws;
        prep_w_kernel<<<(NSRC * H * H + 255) / 256, 256, 0, stream>>>(W, wbuf);
        const int nblk = (n_edges + BM - 1) / BM;
        fused_edge_kernel<<<nblk, 512, 0, stream>>>(nf, senders, receivers, ef, b,
                                                    wbuf, out, n_edges);
    } else {
        naive_edge_kernel<<<(n_edges + 1) / 2, 256, 0, stream>>>(
            nf, senders, receivers, ef, W, b, out, n_edges);
    }

    ln_kernel<<<(n_nodes + 3) / 4, 256, 0, stream>>>(nf, lnw, lnb, out, n_nodes);
}

// Round 4
// 615.656 us; speedup vs baseline: 12.7379x; 1.0253x over previous
//
#include <hip/hip_runtime.h>

#define H 128
#define NSRC 3

typedef _Float16 f16;
typedef _Float16 f16x4 __attribute__((ext_vector_type(4)));
typedef _Float16 f16x8 __attribute__((ext_vector_type(8)));
typedef float f32x4 __attribute__((ext_vector_type(4)));

// ws layout: [0, 96KB): W in f16, per-src [c][k] transposed, PRE-SWIZZLED:
//   byte off within src = (c*256 + k*2) ^ ((c&7)<<4);  src stride 32768 B
// [96KB, 96KB+12.8MB): NF converted to f16, row-major [n][128]

// ---------------------------------------------------------------------------
__global__ void prep_w_kernel(const float* __restrict__ W, f16* __restrict__ wbuf) {
    int g = blockIdx.x * blockDim.x + threadIdx.x;
    if (g >= NSRC * H * H) return;
    int src = g >> 14;
    int k = (g >> 7) & 127;
    int c = g & 127;
    float v = W[((size_t)src * H + k) * H + c];
    unsigned off = ((unsigned)(c * 256 + k * 2)) ^ ((unsigned)((c & 7) << 4));
    wbuf[(size_t)src * (H * H) + (off >> 1)] = (f16)v;
}

// ---------------------------------------------------------------------------
__global__ void prep_nf_kernel(const float* __restrict__ nf, f16* __restrict__ nfh, int n) {
    int i = (blockIdx.x * blockDim.x + threadIdx.x) * 4;
    if (i >= n) return;
    float4 v = *(const float4*)(nf + i);
    f16x4 h;
    h[0] = (f16)v.x; h[1] = (f16)v.y; h[2] = (f16)v.z; h[3] = (f16)v.w;
    *(f16x4*)(nfh + i) = h;
}

// ---------------------------------------------------------------------------
// Barrier-free fused edge GEMM. W (all 3 sources, 96KB f16) staged in LDS
// once; each wave independently computes a 64-edge x 128-col tile:
//   acc = NFh[s]@W1 + NFh[r]@W2 + f16(EF)@W3 ; relu(+b) ; atomicAdd out[r]
// ---------------------------------------------------------------------------
__global__ __launch_bounds__(512, 2)
void fused_edge_kernel(const f16* __restrict__ nfh, const int* __restrict__ senders,
                       const int* __restrict__ receivers, const float* __restrict__ ef,
                       const float* __restrict__ b, const f16* __restrict__ wbuf,
                       float* __restrict__ out, int n_edges) {
    __shared__ __align__(16) f16 Wlds[NSRC * H * H];  // 96 KB

    const int t = threadIdx.x;
    {   // linear copy of pre-swizzled W
        const int4* g = (const int4*)wbuf;
        int4* d = (int4*)Wlds;
#pragma unroll
        for (int i = 0; i < 12; ++i) d[i * 512 + t] = g[i * 512 + t];
    }
    __syncthreads();  // the only barrier

    const int lane = t & 63;
    const int wid = t >> 6;
    const int l15 = lane & 15;
    const int lg = lane >> 4;

    float bias[8];
#pragma unroll
    for (int cf = 0; cf < 8; ++cf) bias[cf] = b[cf * 16 + l15];

    const int ntiles = (n_edges + 63) >> 6;
    const int nworkers = gridDim.x * 8;

    for (int tile = blockIdx.x * 8 + wid; tile < ntiles; tile += nworkers) {
        const int e0 = tile * 64;

        int sid[4], rid[4];
#pragma unroll
        for (int rf = 0; rf < 4; ++rf) {
            int e = e0 + rf * 16 + l15;
            if (e >= n_edges) e = n_edges - 1;
            sid[rf] = senders[e];
            rid[rf] = receivers[e];
        }

        f32x4 acc[4][8];
#pragma unroll
        for (int rf = 0; rf < 4; ++rf)
#pragma unroll
            for (int cf = 0; cf < 8; ++cf) acc[rf][cf] = (f32x4){0.f, 0.f, 0.f, 0.f};

        // ---- phases 0,1: sender / receiver node features (pre-converted f16) ----
#pragma unroll
        for (int src = 0; src < 2; ++src) {
#pragma unroll
            for (int ks = 0; ks < 4; ++ks) {
                f16x8 a[4];
#pragma unroll
                for (int rf = 0; rf < 4; ++rf) {
                    const int row = (src == 0) ? sid[rf] : rid[rf];
                    a[rf] = *(const f16x8*)(nfh + (size_t)row * H + ks * 32 + lg * 8);
                }
#pragma unroll
                for (int cf = 0; cf < 8; ++cf) {
                    const int c = cf * 16 + l15;
                    unsigned off = ((unsigned)(src * 32768 + c * 256 + (ks * 32 + lg * 8) * 2))
                                   ^ ((unsigned)((c & 7) << 4));
                    f16x8 bf = *(const f16x8*)((const char*)Wlds + off);
#pragma unroll
                    for (int rf = 0; rf < 4; ++rf)
                        acc[rf][cf] = __builtin_amdgcn_mfma_f32_16x16x32_f16(
                            a[rf], bf, acc[rf][cf], 0, 0, 0);
                }
            }
        }

        // ---- phase 2: edge features, fp32 -> f16 on the fly ----
#pragma unroll
        for (int ks = 0; ks < 4; ++ks) {
            f16x8 a[4];
#pragma unroll
            for (int rf = 0; rf < 4; ++rf) {
                int e = e0 + rf * 16 + l15;
                if (e >= n_edges) e = n_edges - 1;
                const float* p = ef + (size_t)e * H + ks * 32 + lg * 8;
                float4 v0 = *(const float4*)p;
                float4 v1 = *(const float4*)(p + 4);
                f16x8 h;
                h[0] = (f16)v0.x; h[1] = (f16)v0.y; h[2] = (f16)v0.z; h[3] = (f16)v0.w;
                h[4] = (f16)v1.x; h[5] = (f16)v1.y; h[6] = (f16)v1.z; h[7] = (f16)v1.w;
                a[rf] = h;
            }
#pragma unroll
            for (int cf = 0; cf < 8; ++cf) {
                const int c = cf * 16 + l15;
                unsigned off = ((unsigned)(2 * 32768 + c * 256 + (ks * 32 + lg * 8) * 2))
                               ^ ((unsigned)((c & 7) << 4));
                f16x8 bf = *(const f16x8*)((const char*)Wlds + off);
#pragma unroll
                for (int rf = 0; rf < 4; ++rf)
                    acc[rf][cf] = __builtin_amdgcn_mfma_f32_16x16x32_f16(
                        a[rf], bf, acc[rf][cf], 0, 0, 0);
            }
        }

        // ---- epilogue: bias + relu + atomic scatter ----
        // C/D layout: col = lane&15, row = (lane>>4)*4 + q
#pragma unroll
        for (int rf = 0; rf < 4; ++rf) {
#pragma unroll
            for (int q = 0; q < 4; ++q) {
                const int e = e0 + rf * 16 + lg * 4 + q;
                if (e < n_edges) {
                    const int r = receivers[e];
                    float* dst = out + (size_t)r * H;
#pragma unroll
                    for (int cf = 0; cf < 8; ++cf) {
                        float m = fmaxf(acc[rf][cf][q] + bias[cf], 0.f);
                        atomicAdd(dst + cf * 16 + l15, m);
                    }
                }
            }
        }
    }
}

// ---------------------------------------------------------------------------
// LayerNorm(nf + aggr) in-place on out
// ---------------------------------------------------------------------------
__global__ __launch_bounds__(256, 4)
void ln_kernel(const float* __restrict__ nf, const float* __restrict__ lnw,
               const float* __restrict__ lnb, float* __restrict__ out, int n_nodes) {
    const int wv = threadIdx.x >> 6;
    const int lane = threadIdx.x & 63;
    const int row = blockIdx.x * (blockDim.x >> 6) + wv;
    if (row >= n_nodes) return;
    float2 a = ((const float2*)(nf + (size_t)row * H))[lane];
    float2 g = ((float2*)(out + (size_t)row * H))[lane];
    float vx = a.x + g.x, vy = a.y + g.y;

    float s = vx + vy;
#pragma unroll
    for (int m = 32; m; m >>= 1) s += __shfl_xor(s, m, 64);
    float mu = s * (1.f / H);
    float dx = vx - mu, dy = vy - mu;
    float q = dx * dx + dy * dy;
#pragma unroll
    for (int m = 32; m; m >>= 1) q += __shfl_xor(q, m, 64);
    float rs = rsqrtf(q * (1.f / H) + 1e-5f);

    float2 w2 = ((const float2*)lnw)[lane];
    float2 b2 = ((const float2*)lnb)[lane];
    float2 o;
    o.x = dx * rs * w2.x + b2.x;
    o.y = dy * rs * w2.y + b2.y;
    ((float2*)(out + (size_t)row * H))[lane] = o;
}

// ---------------------------------------------------------------------------
// Fallback (workspace too small): fully naive edge pass
// ---------------------------------------------------------------------------
__global__ void naive_edge_kernel(const float* __restrict__ nf, const int* __restrict__ s,
                                  const int* __restrict__ r, const float* __restrict__ ef,
                                  const float* __restrict__ W, const float* __restrict__ b,
                                  float* __restrict__ out, int n_edges) {
    int e = blockIdx.x * 2 + (threadIdx.x >> 7);
    int c = threadIdx.x & 127;
    if (e >= n_edges) return;
    int se = s[e], re = r[e];
    float acc = b[c];
    for (int k = 0; k < H; ++k) {
        acc += nf[(size_t)se * H + k] * W[(size_t)k * H + c];
        acc += nf[(size_t)re * H + k] * W[(size_t)(H + k) * H + c];
        acc += ef[(size_t)e * H + k] * W[(size_t)(2 * H + k) * H + c];
    }
    atomicAdd(&out[(size_t)re * H + c], fmaxf(acc, 0.f));
}

// ---------------------------------------------------------------------------
extern "C" void kernel_launch(void* const* d_in, const int* in_sizes, int n_in,
                              void* d_out, int out_size, void* d_ws, size_t ws_size,
                              hipStream_t stream) {
    const float* nf        = (const float*)d_in[0];
    const int*   senders   = (const int*)d_in[1];
    const int*   receivers = (const int*)d_in[2];
    const float* ef        = (const float*)d_in[3];
    const float* W         = (const float*)d_in[4];
    const float* b         = (const float*)d_in[5];
    const float* lnw       = (const float*)d_in[6];
    const float* lnb       = (const float*)d_in[7];
    float* out = (float*)d_out;

    const int n_nodes = in_sizes[0] / H;  // 50000
    const int n_edges = in_sizes[1];      // 800000
    const int nfelem = n_nodes * H;

    hipMemsetAsync(d_out, 0, (size_t)n_nodes * H * sizeof(float), stream);

    const size_t w_bytes = (size_t)NSRC * H * H * sizeof(f16);  // 96 KB
    const size_t need = w_bytes + (size_t)nfelem * sizeof(f16);
    if (ws_size >= need) {
        f16* wbuf = (f16*)d_ws;
        f16* nfh = (f16*)((char*)d_ws + w_bytes);
        prep_w_kernel<<<(NSRC * H * H + 255) / 256, 256, 0, stream>>>(W, wbuf);
        prep_nf_kernel<<<(nfelem / 4 + 255) / 256, 256, 0, stream>>>(nf, nfh, nfelem);
        fused_edge_kernel<<<512, 512, 0, stream>>>(nfh, senders, receivers, ef, b,
                                                   wbuf, out, n_edges);
    } else {
        naive_edge_kernel<<<(n_edges + 1) / 2, 256, 0, stream>>>(
            nf, senders, receivers, ef, W, b, out, n_edges);
    }

    ln_kernel<<<(n_nodes + 3) / 4, 256, 0, stream>>>(nf, lnw, lnb, out, n_nodes);
}

// Round 5
// 525.910 us; speedup vs baseline: 14.9117x; 1.1707x over previous
//
#include <hip/hip_runtime.h>

#define H 128
#define NSRC 3

typedef _Float16 f16;
typedef _Float16 f16x2 __attribute__((ext_vector_type(2)));
typedef _Float16 f16x4 __attribute__((ext_vector_type(4)));
typedef _Float16 f16x8 __attribute__((ext_vector_type(8)));
typedef float f32x4 __attribute__((ext_vector_type(4)));

// ---------------------------------------------------------------------------
// prep W: fp32 [384][128] -> f16 per-src [c][k] transposed, PRE-SWIZZLED
//   byte off within src = (c*256 + k*2) ^ ((c&7)<<4); src stride 32768 B
// ---------------------------------------------------------------------------
__global__ void prep_w_kernel(const float* __restrict__ W, f16* __restrict__ wbuf) {
    int g = blockIdx.x * blockDim.x + threadIdx.x;
    if (g >= NSRC * H * H) return;
    int src = g >> 14;
    int k = (g >> 7) & 127;
    int c = g & 127;
    float v = W[((size_t)src * H + k) * H + c];
    unsigned off = ((unsigned)(c * 256 + k * 2)) ^ ((unsigned)((c & 7) << 4));
    wbuf[(size_t)src * (H * H) + (off >> 1)] = (f16)v;
}

// ---------------------------------------------------------------------------
__global__ void prep_nf_kernel(const float* __restrict__ nf, f16* __restrict__ nfh, int n) {
    int i = (blockIdx.x * blockDim.x + threadIdx.x) * 4;
    if (i >= n) return;
    float4 v = *(const float4*)(nf + i);
    f16x4 h;
    h[0] = (f16)v.x; h[1] = (f16)v.y; h[2] = (f16)v.z; h[3] = (f16)v.w;
    *(f16x4*)(nfh + i) = h;
}

// ---------------------------------------------------------------------------
// Counting sort by receiver: hist -> scan -> scatter
// ---------------------------------------------------------------------------
__global__ void hist_kernel(const int* __restrict__ recv, int* __restrict__ cnt, int n_edges) {
    int e = blockIdx.x * blockDim.x + threadIdx.x;
    if (e < n_edges) atomicAdd(&cnt[recv[e]], 1);
}

__global__ void scan_kernel(const int* __restrict__ cnt, int* __restrict__ row_ptr,
                            int* __restrict__ cursor, int n) {
    __shared__ int sd[1024];
    const int t = threadIdx.x;
    const int per = (n + 1023) >> 10;
    const int st = t * per;
    const int en = min(st + per, n);
    int s = 0;
    for (int i = st; i < en; ++i) s += cnt[i];
    sd[t] = s;
    __syncthreads();
    for (int off = 1; off < 1024; off <<= 1) {
        int v = 0;
        if (t >= off) v = sd[t - off];
        __syncthreads();
        sd[t] += v;
        __syncthreads();
    }
    int base = sd[t] - s;  // exclusive prefix of this chunk
    int run = base;
    for (int i = st; i < en; ++i) {
        row_ptr[i] = run;
        cursor[i] = run;
        run += cnt[i];
    }
    if (t == 1023) row_ptr[n] = sd[1023];
}

__global__ void scatter_kernel(const int* __restrict__ send, const int* __restrict__ recv,
                               int* __restrict__ cursor, int* __restrict__ perm,
                               int* __restrict__ ssend, int n_edges) {
    int e = blockIdx.x * blockDim.x + threadIdx.x;
    if (e < n_edges) {
        int r = recv[e];
        int pos = atomicAdd(&cursor[r], 1);
        perm[pos] = e;
        ssend[pos] = send[e];
    }
}

// ---------------------------------------------------------------------------
// Node projections: PS = NFh@W1 (f16 out), PR = NFh@W2 + b (fp32 out)
// ---------------------------------------------------------------------------
__global__ __launch_bounds__(256, 2)
void node_proj_kernel(const f16* __restrict__ nfh, const float* __restrict__ b,
                      const f16* __restrict__ wbuf, f16* __restrict__ PS,
                      float* __restrict__ PR, int n_nodes) {
    __shared__ __align__(16) f16 Wlds[2 * H * H];  // 64 KB: W1, W2
    const int t = threadIdx.x;
    {
        const int4* g = (const int4*)wbuf;
        int4* d = (int4*)Wlds;
#pragma unroll
        for (int i = 0; i < 16; ++i) d[i * 256 + t] = g[i * 256 + t];
    }
    __syncthreads();

    const int lane = t & 63;
    const int wid = t >> 6;
    const int l15 = lane & 15;
    const int lg = lane >> 4;
    const int r0 = (blockIdx.x * 4 + wid) * 64;
    if (r0 >= n_nodes) return;

#pragma unroll
    for (int src = 0; src < 2; ++src) {
        f32x4 acc[4][8];
#pragma unroll
        for (int rf = 0; rf < 4; ++rf)
#pragma unroll
            for (int cf = 0; cf < 8; ++cf) acc[rf][cf] = (f32x4){0.f, 0.f, 0.f, 0.f};

#pragma unroll
        for (int ks = 0; ks < 4; ++ks) {
            f16x8 a[4];
#pragma unroll
            for (int rf = 0; rf < 4; ++rf) {
                int row = r0 + rf * 16 + l15;
                if (row >= n_nodes) row = n_nodes - 1;
                a[rf] = *(const f16x8*)(nfh + (size_t)row * H + ks * 32 + lg * 8);
            }
#pragma unroll
            for (int cf = 0; cf < 8; ++cf) {
                const int c = cf * 16 + l15;
                unsigned off = ((unsigned)(src * 32768 + c * 256 + (ks * 32 + lg * 8) * 2))
                               ^ ((unsigned)((c & 7) << 4));
                f16x8 bf = *(const f16x8*)((const char*)Wlds + off);
#pragma unroll
                for (int rf = 0; rf < 4; ++rf)
                    acc[rf][cf] = __builtin_amdgcn_mfma_f32_16x16x32_f16(
                        a[rf], bf, acc[rf][cf], 0, 0, 0);
            }
        }

#pragma unroll
        for (int rf = 0; rf < 4; ++rf) {
#pragma unroll
            for (int q = 0; q < 4; ++q) {
                const int row = r0 + rf * 16 + lg * 4 + q;
                if (row < n_nodes) {
#pragma unroll
                    for (int cf = 0; cf < 8; ++cf) {
                        const int col = cf * 16 + l15;
                        if (src == 0)
                            PS[(size_t)row * H + col] = (f16)acc[rf][cf][q];
                        else
                            PR[(size_t)row * H + col] = acc[rf][cf][q] + b[col];
                    }
                }
            }
        }
    }
}

// ---------------------------------------------------------------------------
// Edge GEMM over sorted order: ME[i] = f16(EF[perm[i]]) @ W3, f16 stores
// ---------------------------------------------------------------------------
__global__ __launch_bounds__(256, 2)
void edge_gemm_kernel(const float* __restrict__ ef, const int* __restrict__ perm,
                      const f16* __restrict__ wbuf, f16* __restrict__ ME, int n_edges) {
    __shared__ __align__(16) f16 Wlds[H * H];  // 32 KB: W3
    const int t = threadIdx.x;
    {
        const int4* g = (const int4*)(wbuf + (size_t)2 * H * H);
        int4* d = (int4*)Wlds;
#pragma unroll
        for (int i = 0; i < 8; ++i) d[i * 256 + t] = g[i * 256 + t];
    }
    __syncthreads();

    const int lane = t & 63;
    const int wid = t >> 6;
    const int l15 = lane & 15;
    const int lg = lane >> 4;
    const int e0 = (blockIdx.x * 4 + wid) * 64;
    if (e0 >= n_edges) return;

    int pe[4];
#pragma unroll
    for (int rf = 0; rf < 4; ++rf) {
        int e = e0 + rf * 16 + l15;
        if (e >= n_edges) e = n_edges - 1;
        pe[rf] = perm[e];
    }

    f32x4 acc[4][8];
#pragma unroll
    for (int rf = 0; rf < 4; ++rf)
#pragma unroll
        for (int cf = 0; cf < 8; ++cf) acc[rf][cf] = (f32x4){0.f, 0.f, 0.f, 0.f};

#pragma unroll
    for (int ks = 0; ks < 4; ++ks) {
        f16x8 a[4];
#pragma unroll
        for (int rf = 0; rf < 4; ++rf) {
            const float* p = ef + (size_t)pe[rf] * H + ks * 32 + lg * 8;
            float4 v0 = *(const float4*)p;
            float4 v1 = *(const float4*)(p + 4);
            f16x8 h;
            h[0] = (f16)v0.x; h[1] = (f16)v0.y; h[2] = (f16)v0.z; h[3] = (f16)v0.w;
            h[4] = (f16)v1.x; h[5] = (f16)v1.y; h[6] = (f16)v1.z; h[7] = (f16)v1.w;
            a[rf] = h;
        }
#pragma unroll
        for (int cf = 0; cf < 8; ++cf) {
            const int c = cf * 16 + l15;
            unsigned off = ((unsigned)(c * 256 + (ks * 32 + lg * 8) * 2))
                           ^ ((unsigned)((c & 7) << 4));
            f16x8 bf = *(const f16x8*)((const char*)Wlds + off);
#pragma unroll
            for (int rf = 0; rf < 4; ++rf)
                acc[rf][cf] = __builtin_amdgcn_mfma_f32_16x16x32_f16(
                    a[rf], bf, acc[rf][cf], 0, 0, 0);
        }
    }

#pragma unroll
    for (int rf = 0; rf < 4; ++rf) {
#pragma unroll
        for (int q = 0; q < 4; ++q) {
            const int e = e0 + rf * 16 + lg * 4 + q;
            if (e < n_edges) {
#pragma unroll
                for (int cf = 0; cf < 8; ++cf)
                    ME[(size_t)e * H + cf * 16 + l15] = (f16)acc[rf][cf][q];
            }
        }
    }
}

// ---------------------------------------------------------------------------
// Aggregate + residual + LayerNorm, one wave per node, plain stores.
// aggr[n] = sum over sorted segment [row_ptr[n], row_ptr[n+1]) of
//           relu(PS[ssend[i]] + PR[n] + ME[i])
// ---------------------------------------------------------------------------
__global__ __launch_bounds__(256, 4)
void aggregate_ln_kernel(const float* __restrict__ nf, const f16* __restrict__ PS,
                         const float* __restrict__ PR, const f16* __restrict__ ME,
                         const int* __restrict__ row_ptr, const int* __restrict__ ssend,
                         const float* __restrict__ lnw, const float* __restrict__ lnb,
                         float* __restrict__ out, int n_nodes) {
    const int wv = threadIdx.x >> 6;
    const int lane = threadIdx.x & 63;
    const int n = blockIdx.x * 4 + wv;
    if (n >= n_nodes) return;
    const int c2 = lane * 2;

    float2 pr = *(const float2*)&PR[(size_t)n * H + c2];
    const int beg = row_ptr[n];
    const int end = row_ptr[n + 1];

    float ax = 0.f, ay = 0.f;
    for (int i = beg; i < end; ++i) {
        const int s = ssend[i];
        f16x2 me = *(const f16x2*)&ME[(size_t)i * H + c2];
        f16x2 ps = *(const f16x2*)&PS[(size_t)s * H + c2];
        ax += fmaxf((float)ps[0] + pr.x + (float)me[0], 0.f);
        ay += fmaxf((float)ps[1] + pr.y + (float)me[1], 0.f);
    }

    float2 a2 = *(const float2*)&nf[(size_t)n * H + c2];
    float vx = a2.x + ax, vy = a2.y + ay;

    float s = vx + vy;
#pragma unroll
    for (int m = 32; m; m >>= 1) s += __shfl_xor(s, m, 64);
    float mu = s * (1.f / H);
    float dx = vx - mu, dy = vy - mu;
    float q = dx * dx + dy * dy;
#pragma unroll
    for (int m = 32; m; m >>= 1) q += __shfl_xor(q, m, 64);
    float rs = rsqrtf(q * (1.f / H) + 1e-5f);

    float2 w2 = ((const float2*)lnw)[lane];
    float2 b2 = ((const float2*)lnb)[lane];
    float2 o;
    o.x = dx * rs * w2.x + b2.x;
    o.y = dy * rs * w2.y + b2.y;
    *(float2*)&out[(size_t)n * H + c2] = o;
}

// ---------------------------------------------------------------------------
// Fallback path (R4): barrier-free fused GEMM with atomics + separate LN
// ---------------------------------------------------------------------------
__global__ __launch_bounds__(512, 2)
void fused_edge_kernel(const f16* __restrict__ nfh, const int* __restrict__ senders,
                       const int* __restrict__ receivers, const float* __restrict__ ef,
                       const float* __restrict__ b, const f16* __restrict__ wbuf,
                       float* __restrict__ out, int n_edges) {
    __shared__ __align__(16) f16 Wlds[NSRC * H * H];  // 96 KB
    const int t = threadIdx.x;
    {
        const int4* g = (const int4*)wbuf;
        int4* d = (int4*)Wlds;
#pragma unroll
        for (int i = 0; i < 12; ++i) d[i * 512 + t] = g[i * 512 + t];
    }
    __syncthreads();

    const int lane = t & 63;
    const int wid = t >> 6;
    const int l15 = lane & 15;
    const int lg = lane >> 4;

    float bias[8];
#pragma unroll
    for (int cf = 0; cf < 8; ++cf) bias[cf] = b[cf * 16 + l15];

    const int ntiles = (n_edges + 63) >> 6;
    const int nworkers = gridDim.x * 8;

    for (int tile = blockIdx.x * 8 + wid; tile < ntiles; tile += nworkers) {
        const int e0 = tile * 64;
        int sid[4], rid[4];
#pragma unroll
        for (int rf = 0; rf < 4; ++rf) {
            int e = e0 + rf * 16 + l15;
            if (e >= n_edges) e = n_edges - 1;
            sid[rf] = senders[e];
            rid[rf] = receivers[e];
        }
        f32x4 acc[4][8];
#pragma unroll
        for (int rf = 0; rf < 4; ++rf)
#pragma unroll
            for (int cf = 0; cf < 8; ++cf) acc[rf][cf] = (f32x4){0.f, 0.f, 0.f, 0.f};

#pragma unroll
        for (int src = 0; src < 2; ++src) {
#pragma unroll
            for (int ks = 0; ks < 4; ++ks) {
                f16x8 a[4];
#pragma unroll
                for (int rf = 0; rf < 4; ++rf) {
                    const int row = (src == 0) ? sid[rf] : rid[rf];
                    a[rf] = *(const f16x8*)(nfh + (size_t)row * H + ks * 32 + lg * 8);
                }
#pragma unroll
                for (int cf = 0; cf < 8; ++cf) {
                    const int c = cf * 16 + l15;
                    unsigned off = ((unsigned)(src * 32768 + c * 256 + (ks * 32 + lg * 8) * 2))
                                   ^ ((unsigned)((c & 7) << 4));
                    f16x8 bf = *(const f16x8*)((const char*)Wlds + off);
#pragma unroll
                    for (int rf = 0; rf < 4; ++rf)
                        acc[rf][cf] = __builtin_amdgcn_mfma_f32_16x16x32_f16(
                            a[rf], bf, acc[rf][cf], 0, 0, 0);
                }
            }
        }
#pragma unroll
        for (int ks = 0; ks < 4; ++ks) {
            f16x8 a[4];
#pragma unroll
            for (int rf = 0; rf < 4; ++rf) {
                int e = e0 + rf * 16 + l15;
                if (e >= n_edges) e = n_edges - 1;
                const float* p = ef + (size_t)e * H + ks * 32 + lg * 8;
                float4 v0 = *(const float4*)p;
                float4 v1 = *(const float4*)(p + 4);
                f16x8 h;
                h[0] = (f16)v0.x; h[1] = (f16)v0.y; h[2] = (f16)v0.z; h[3] = (f16)v0.w;
                h[4] = (f16)v1.x; h[5] = (f16)v1.y; h[6] = (f16)v1.z; h[7] = (f16)v1.w;
                a[rf] = h;
            }
#pragma unroll
            for (int cf = 0; cf < 8; ++cf) {
                const int c = cf * 16 + l15;
                unsigned off = ((unsigned)(2 * 32768 + c * 256 + (ks * 32 + lg * 8) * 2))
                               ^ ((unsigned)((c & 7) << 4));
                f16x8 bf = *(const f16x8*)((const char*)Wlds + off);
#pragma unroll
                for (int rf = 0; rf < 4; ++rf)
                    acc[rf][cf] = __builtin_amdgcn_mfma_f32_16x16x32_f16(
                        a[rf], bf, acc[rf][cf], 0, 0, 0);
            }
        }
#pragma unroll
        for (int rf = 0; rf < 4; ++rf) {
#pragma unroll
            for (int q = 0; q < 4; ++q) {
                const int e = e0 + rf * 16 + lg * 4 + q;
                if (e < n_edges) {
                    const int r = receivers[e];
                    float* dst = out + (size_t)r * H;
#pragma unroll
                    for (int cf = 0; cf < 8; ++cf) {
                        float m = fmaxf(acc[rf][cf][q] + bias[cf], 0.f);
                        atomicAdd(dst + cf * 16 + l15, m);
                    }
                }
            }
        }
    }
}

__global__ __launch_bounds__(256, 4)
void ln_kernel(const float* __restrict__ nf, const float* __restrict__ lnw,
               const float* __restrict__ lnb, float* __restrict__ out, int n_nodes) {
    const int wv = threadIdx.x >> 6;
    const int lane = threadIdx.x & 63;
    const int row = blockIdx.x * (blockDim.x >> 6) + wv;
    if (row >= n_nodes) return;
    float2 a = ((const float2*)(nf + (size_t)row * H))[lane];
    float2 g = ((float2*)(out + (size_t)row * H))[lane];
    float vx = a.x + g.x, vy = a.y + g.y;
    float s = vx + vy;
#pragma unroll
    for (int m = 32; m; m >>= 1) s += __shfl_xor(s, m, 64);
    float mu = s * (1.f / H);
    float dx = vx - mu, dy = vy - mu;
    float q = dx * dx + dy * dy;
#pragma unroll
    for (int m = 32; m; m >>= 1) q += __shfl_xor(q, m, 64);
    float rs = rsqrtf(q * (1.f / H) + 1e-5f);
    float2 w2 = ((const float2*)lnw)[lane];
    float2 b2 = ((const float2*)lnb)[lane];
    float2 o;
    o.x = dx * rs * w2.x + b2.x;
    o.y = dy * rs * w2.y + b2.y;
    ((float2*)(out + (size_t)row * H))[lane] = o;
}

__global__ void naive_edge_kernel(const float* __restrict__ nf, const int* __restrict__ s,
                                  const int* __restrict__ r, const float* __restrict__ ef,
                                  const float* __restrict__ W, const float* __restrict__ b,
                                  float* __restrict__ out, int n_edges) {
    int e = blockIdx.x * 2 + (threadIdx.x >> 7);
    int c = threadIdx.x & 127;
    if (e >= n_edges) return;
    int se = s[e], re = r[e];
    float acc = b[c];
    for (int k = 0; k < H; ++k) {
        acc += nf[(size_t)se * H + k] * W[(size_t)k * H + c];
        acc += nf[(size_t)re * H + k] * W[(size_t)(H + k) * H + c];
        acc += ef[(size_t)e * H + k] * W[(size_t)(2 * H + k) * H + c];
    }
    atomicAdd(&out[(size_t)re * H + c], fmaxf(acc, 0.f));
}

// ---------------------------------------------------------------------------
extern "C" void kernel_launch(void* const* d_in, const int* in_sizes, int n_in,
                              void* d_out, int out_size, void* d_ws, size_t ws_size,
                              hipStream_t stream) {
    const float* nf        = (const float*)d_in[0];
    const int*   senders   = (const int*)d_in[1];
    const int*   receivers = (const int*)d_in[2];
    const float* ef        = (const float*)d_in[3];
    const float* W         = (const float*)d_in[4];
    const float* b         = (const float*)d_in[5];
    const float* lnw       = (const float*)d_in[6];
    const float* lnb       = (const float*)d_in[7];
    float* out = (float*)d_out;

    const int n_nodes = in_sizes[0] / H;  // 50000
    const int n_edges = in_sizes[1];      // 800000
    const int nfelem = n_nodes * H;

    // ws carve-out (256B aligned)
    size_t o = 0;
    auto carve = [&](size_t bytes) { size_t r = o; o += (bytes + 255) & ~(size_t)255; return r; };
    const size_t o_wbuf   = carve((size_t)NSRC * H * H * sizeof(f16));   // 96 KB
    const size_t o_nfh    = carve((size_t)nfelem * sizeof(f16));         // 12.8 MB
    const size_t o_cnt    = carve((size_t)n_nodes * 4);
    const size_t o_rowptr = carve((size_t)(n_nodes + 1) * 4);
    const size_t o_cursor = carve((size_t)n_nodes * 4);
    const size_t o_perm   = carve((size_t)n_edges * 4);
    const size_t o_ssend  = carve((size_t)n_edges * 4);
    const size_t o_ps     = carve((size_t)nfelem * sizeof(f16));         // 12.8 MB
    const size_t o_pr     = carve((size_t)nfelem * sizeof(float));       // 25.6 MB
    const size_t o_me     = carve((size_t)n_edges * H * sizeof(f16));    // 204.8 MB
    const size_t need_full = o;

    char* ws = (char*)d_ws;
    f16* wbuf = (f16*)(ws + o_wbuf);
    f16* nfh  = (f16*)(ws + o_nfh);

    if (ws_size >= need_full) {
        int* cnt    = (int*)(ws + o_cnt);
        int* rowptr = (int*)(ws + o_rowptr);
        int* cursor = (int*)(ws + o_cursor);
        int* perm   = (int*)(ws + o_perm);
        int* ssend  = (int*)(ws + o_ssend);
        f16* PS     = (f16*)(ws + o_ps);
        float* PR   = (float*)(ws + o_pr);
        f16* ME     = (f16*)(ws + o_me);

        hipMemsetAsync(cnt, 0, (size_t)n_nodes * 4, stream);
        prep_w_kernel<<<(NSRC * H * H + 255) / 256, 256, 0, stream>>>(W, wbuf);
        prep_nf_kernel<<<(nfelem / 4 + 255) / 256, 256, 0, stream>>>(nf, nfh, nfelem);
        hist_kernel<<<(n_edges + 255) / 256, 256, 0, stream>>>(receivers, cnt, n_edges);
        scan_kernel<<<1, 1024, 0, stream>>>(cnt, rowptr, cursor, n_nodes);
        scatter_kernel<<<(n_edges + 255) / 256, 256, 0, stream>>>(
            senders, receivers, cursor, perm, ssend, n_edges);

        const int ntile_n = (n_nodes + 63) / 64;
        node_proj_kernel<<<(ntile_n + 3) / 4, 256, 0, stream>>>(nfh, b, wbuf, PS, PR, n_nodes);
        const int ntile_e = (n_edges + 63) / 64;
        edge_gemm_kernel<<<(ntile_e + 3) / 4, 256, 0, stream>>>(ef, perm, wbuf, ME, n_edges);
        aggregate_ln_kernel<<<(n_nodes + 3) / 4, 256, 0, stream>>>(
            nf, PS, PR, ME, rowptr, ssend, lnw, lnb, out, n_nodes);
    } else if (ws_size >= o_cnt) {  // enough for wbuf + nfh: R4 fallback
        hipMemsetAsync(d_out, 0, (size_t)nfelem * sizeof(float), stream);
        prep_w_kernel<<<(NSRC * H * H + 255) / 256, 256, 0, stream>>>(W, wbuf);
        prep_nf_kernel<<<(nfelem / 4 + 255) / 256, 256, 0, stream>>>(nf, nfh, nfelem);
        fused_edge_kernel<<<512, 512, 0, stream>>>(nfh, senders, receivers, ef, b,
                                                   wbuf, out, n_edges);
        ln_kernel<<<(n_nodes + 3) / 4, 256, 0, stream>>>(nf, lnw, lnb, out, n_nodes);
    } else {
        hipMemsetAsync(d_out, 0, (size_t)nfelem * sizeof(float), stream);
        naive_edge_kernel<<<(n_edges + 1) / 2, 256, 0, stream>>>(
            nf, senders, receivers, ef, W, b, out, n_edges);
        ln_kernel<<<(n_nodes + 3) / 4, 256, 0, stream>>>(nf, lnw, lnb, out, n_nodes);
    }
}

// Round 6
// 480.888 us; speedup vs baseline: 16.3077x; 1.0936x over previous
//
#include <hip/hip_runtime.h>

#define H 128
#define NSRC 3

typedef _Float16 f16;
typedef _Float16 f16x2 __attribute__((ext_vector_type(2)));
typedef _Float16 f16x4 __attribute__((ext_vector_type(4)));
typedef _Float16 f16x8 __attribute__((ext_vector_type(8)));
typedef float f32x4 __attribute__((ext_vector_type(4)));

// ---------------------------------------------------------------------------
__global__ void zero_kernel(int* __restrict__ p, int n) {
    int i = blockIdx.x * blockDim.x + threadIdx.x;
    if (i < n) p[i] = 0;
}

// ---------------------------------------------------------------------------
// prep W: fp32 [384][128] -> f16 per-src [c][k] transposed, PRE-SWIZZLED
//   byte off within src = (c*256 + k*2) ^ ((c&7)<<4); src stride 32768 B
// ---------------------------------------------------------------------------
__global__ void prep_w_kernel(const float* __restrict__ W, f16* __restrict__ wbuf) {
    int g = blockIdx.x * blockDim.x + threadIdx.x;
    if (g >= NSRC * H * H) return;
    int src = g >> 14;
    int k = (g >> 7) & 127;
    int c = g & 127;
    float v = W[((size_t)src * H + k) * H + c];
    unsigned off = ((unsigned)(c * 256 + k * 2)) ^ ((unsigned)((c & 7) << 4));
    wbuf[(size_t)src * (H * H) + (off >> 1)] = (f16)v;
}

// ---------------------------------------------------------------------------
__global__ void prep_nf_kernel(const float* __restrict__ nf, f16* __restrict__ nfh, int n) {
    int i = (blockIdx.x * blockDim.x + threadIdx.x) * 4;
    if (i >= n) return;
    float4 v = *(const float4*)(nf + i);
    f16x4 h;
    h[0] = (f16)v.x; h[1] = (f16)v.y; h[2] = (f16)v.z; h[3] = (f16)v.w;
    *(f16x4*)(nfh + i) = h;
}

// ---------------------------------------------------------------------------
// Counting sort by receiver: hist -> scan -> scatter (emits inverse perm)
// ---------------------------------------------------------------------------
__global__ void hist_kernel(const int* __restrict__ recv, int* __restrict__ cnt, int n_edges) {
    int e = blockIdx.x * blockDim.x + threadIdx.x;
    if (e < n_edges) atomicAdd(&cnt[recv[e]], 1);
}

__global__ void scan_kernel(const int* __restrict__ cnt, int* __restrict__ row_ptr,
                            int* __restrict__ cursor, int n) {
    __shared__ int sd[1024];
    const int t = threadIdx.x;
    const int per = (n + 1023) >> 10;
    const int st = t * per;
    const int en = min(st + per, n);
    int s = 0;
    for (int i = st; i < en; ++i) s += cnt[i];
    sd[t] = s;
    __syncthreads();
    for (int off = 1; off < 1024; off <<= 1) {
        int v = 0;
        if (t >= off) v = sd[t - off];
        __syncthreads();
        sd[t] += v;
        __syncthreads();
    }
    int run = sd[t] - s;  // exclusive prefix of this chunk
    for (int i = st; i < en; ++i) {
        row_ptr[i] = run;
        cursor[i] = run;
        run += cnt[i];
    }
    if (t == 1023) row_ptr[n] = sd[1023];
}

__global__ void scatter_kernel(const int* __restrict__ send, const int* __restrict__ recv,
                               int* __restrict__ cursor, int* __restrict__ spos,
                               int* __restrict__ ssend, int n_edges) {
    int e = blockIdx.x * blockDim.x + threadIdx.x;
    if (e < n_edges) {
        int r = recv[e];
        int pos = atomicAdd(&cursor[r], 1);
        spos[e] = pos;        // sequential write: inverse permutation
        ssend[pos] = send[e]; // scattered 4B write (sorted senders)
    }
}

// ---------------------------------------------------------------------------
// Node projections (fp32 in, convert on the fly):
//   PS = f16(NF)@W1 (f16 out), PR = f16(NF)@W2 + b (fp32 out)
// ---------------------------------------------------------------------------
__global__ __launch_bounds__(256, 2)
void node_proj_kernel(const float* __restrict__ nf, const float* __restrict__ b,
                      const f16* __restrict__ wbuf, f16* __restrict__ PS,
                      float* __restrict__ PR, int n_nodes) {
    __shared__ __align__(16) f16 Wlds[2 * H * H];  // 64 KB: W1, W2
    const int t = threadIdx.x;
    {
        const int4* g = (const int4*)wbuf;
        int4* d = (int4*)Wlds;
#pragma unroll
        for (int i = 0; i < 16; ++i) d[i * 256 + t] = g[i * 256 + t];
    }
    __syncthreads();

    const int lane = t & 63;
    const int wid = t >> 6;
    const int l15 = lane & 15;
    const int lg = lane >> 4;
    const int r0 = (blockIdx.x * 4 + wid) * 64;
    if (r0 >= n_nodes) return;

#pragma unroll
    for (int src = 0; src < 2; ++src) {
        f32x4 acc[4][8];
#pragma unroll
        for (int rf = 0; rf < 4; ++rf)
#pragma unroll
            for (int cf = 0; cf < 8; ++cf) acc[rf][cf] = (f32x4){0.f, 0.f, 0.f, 0.f};

#pragma unroll
        for (int ks = 0; ks < 4; ++ks) {
            f16x8 a[4];
#pragma unroll
            for (int rf = 0; rf < 4; ++rf) {
                int row = r0 + rf * 16 + l15;
                if (row >= n_nodes) row = n_nodes - 1;
                const float* p = nf + (size_t)row * H + ks * 32 + lg * 8;
                float4 v0 = *(const float4*)p;
                float4 v1 = *(const float4*)(p + 4);
                f16x8 h;
                h[0] = (f16)v0.x; h[1] = (f16)v0.y; h[2] = (f16)v0.z; h[3] = (f16)v0.w;
                h[4] = (f16)v1.x; h[5] = (f16)v1.y; h[6] = (f16)v1.z; h[7] = (f16)v1.w;
                a[rf] = h;
            }
#pragma unroll
            for (int cf = 0; cf < 8; ++cf) {
                const int c = cf * 16 + l15;
                unsigned off = ((unsigned)(src * 32768 + c * 256 + (ks * 32 + lg * 8) * 2))
                               ^ ((unsigned)((c & 7) << 4));
                f16x8 bf = *(const f16x8*)((const char*)Wlds + off);
#pragma unroll
                for (int rf = 0; rf < 4; ++rf)
                    acc[rf][cf] = __builtin_amdgcn_mfma_f32_16x16x32_f16(
                        a[rf], bf, acc[rf][cf], 0, 0, 0);
            }
        }

#pragma unroll
        for (int rf = 0; rf < 4; ++rf) {
#pragma unroll
            for (int q = 0; q < 4; ++q) {
                const int row = r0 + rf * 16 + lg * 4 + q;
                if (row < n_nodes) {
#pragma unroll
                    for (int cf = 0; cf < 8; ++cf) {
                        const int col = cf * 16 + l15;
                        if (src == 0)
                            PS[(size_t)row * H + col] = (f16)acc[rf][cf][q];
                        else
                            PR[(size_t)row * H + col] = acc[rf][cf][q] + b[col];
                    }
                }
            }
        }
    }
}

// ---------------------------------------------------------------------------
// Edge GEMM in EDGE order (EF streamed sequentially):
//   row = f16(EF[e]) @ W3, scatter-stored to ME[spos[e]] (f16)
// ---------------------------------------------------------------------------
__global__ __launch_bounds__(256, 2)
void edge_gemm_kernel(const float* __restrict__ ef, const int* __restrict__ spos,
                      const f16* __restrict__ wbuf, f16* __restrict__ ME, int n_edges) {
    __shared__ __align__(16) f16 Wlds[H * H];  // 32 KB: W3
    const int t = threadIdx.x;
    {
        const int4* g = (const int4*)(wbuf + (size_t)2 * H * H);
        int4* d = (int4*)Wlds;
#pragma unroll
        for (int i = 0; i < 8; ++i) d[i * 256 + t] = g[i * 256 + t];
    }
    __syncthreads();

    const int lane = t & 63;
    const int wid = t >> 6;
    const int l15 = lane & 15;
    const int lg = lane >> 4;
    const int e0 = (blockIdx.x * 4 + wid) * 64;
    if (e0 >= n_edges) return;

    f32x4 acc[4][8];
#pragma unroll
    for (int rf = 0; rf < 4; ++rf)
#pragma unroll
        for (int cf = 0; cf < 8; ++cf) acc[rf][cf] = (f32x4){0.f, 0.f, 0.f, 0.f};

#pragma unroll
    for (int ks = 0; ks < 4; ++ks) {
        f16x8 a[4];
#pragma unroll
        for (int rf = 0; rf < 4; ++rf) {
            int e = e0 + rf * 16 + l15;
            if (e >= n_edges) e = n_edges - 1;
            const float* p = ef + (size_t)e * H + ks * 32 + lg * 8;
            float4 v0 = *(const float4*)p;
            float4 v1 = *(const float4*)(p + 4);
            f16x8 h;
            h[0] = (f16)v0.x; h[1] = (f16)v0.y; h[2] = (f16)v0.z; h[3] = (f16)v0.w;
            h[4] = (f16)v1.x; h[5] = (f16)v1.y; h[6] = (f16)v1.z; h[7] = (f16)v1.w;
            a[rf] = h;
        }
#pragma unroll
        for (int cf = 0; cf < 8; ++cf) {
            const int c = cf * 16 + l15;
            unsigned off = ((unsigned)(c * 256 + (ks * 32 + lg * 8) * 2))
                           ^ ((unsigned)((c & 7) << 4));
            f16x8 bf = *(const f16x8*)((const char*)Wlds + off);
#pragma unroll
            for (int rf = 0; rf < 4; ++rf)
                acc[rf][cf] = __builtin_amdgcn_mfma_f32_16x16x32_f16(
                    a[rf], bf, acc[rf][cf], 0, 0, 0);
        }
    }

#pragma unroll
    for (int rf = 0; rf < 4; ++rf) {
#pragma unroll
        for (int q = 0; q < 4; ++q) {
            const int e = e0 + rf * 16 + lg * 4 + q;
            if (e < n_edges) {
                const size_t sp = (size_t)spos[e];
#pragma unroll
                for (int cf = 0; cf < 8; ++cf)
                    ME[sp * H + cf * 16 + l15] = (f16)acc[rf][cf][q];
            }
        }
    }
}

// ---------------------------------------------------------------------------
// Aggregate + residual + LayerNorm, one wave per node, plain stores.
// ME is in sorted order -> sequential; PS gather is L2/L3-served.
// ---------------------------------------------------------------------------
__global__ __launch_bounds__(256, 4)
void aggregate_ln_kernel(const float* __restrict__ nf, const f16* __restrict__ PS,
                         const float* __restrict__ PR, const f16* __restrict__ ME,
                         const int* __restrict__ row_ptr, const int* __restrict__ ssend,
                         const float* __restrict__ lnw, const float* __restrict__ lnb,
                         float* __restrict__ out, int n_nodes) {
    const int wv = threadIdx.x >> 6;
    const int lane = threadIdx.x & 63;
    const int n = blockIdx.x * 4 + wv;
    if (n >= n_nodes) return;
    const int c2 = lane * 2;

    float2 pr = *(const float2*)&PR[(size_t)n * H + c2];
    const int beg = row_ptr[n];
    const int end = row_ptr[n + 1];

    float ax = 0.f, ay = 0.f;
    int i = beg;
    for (; i + 2 <= end; i += 2) {
        const int s0 = ssend[i];
        const int s1 = ssend[i + 1];
        f16x2 me0 = *(const f16x2*)&ME[(size_t)i * H + c2];
        f16x2 me1 = *(const f16x2*)&ME[(size_t)(i + 1) * H + c2];
        f16x2 ps0 = *(const f16x2*)&PS[(size_t)s0 * H + c2];
        f16x2 ps1 = *(const f16x2*)&PS[(size_t)s1 * H + c2];
        ax += fmaxf((float)ps0[0] + pr.x + (float)me0[0], 0.f);
        ay += fmaxf((float)ps0[1] + pr.y + (float)me0[1], 0.f);
        ax += fmaxf((float)ps1[0] + pr.x + (float)me1[0], 0.f);
        ay += fmaxf((float)ps1[1] + pr.y + (float)me1[1], 0.f);
    }
    if (i < end) {
        const int s0 = ssend[i];
        f16x2 me0 = *(const f16x2*)&ME[(size_t)i * H + c2];
        f16x2 ps0 = *(const f16x2*)&PS[(size_t)s0 * H + c2];
        ax += fmaxf((float)ps0[0] + pr.x + (float)me0[0], 0.f);
        ay += fmaxf((float)ps0[1] + pr.y + (float)me0[1], 0.f);
    }

    float2 a2 = *(const float2*)&nf[(size_t)n * H + c2];
    float vx = a2.x + ax, vy = a2.y + ay;

    float s = vx + vy;
#pragma unroll
    for (int m = 32; m; m >>= 1) s += __shfl_xor(s, m, 64);
    float mu = s * (1.f / H);
    float dx = vx - mu, dy = vy - mu;
    float q = dx * dx + dy * dy;
#pragma unroll
    for (int m = 32; m; m >>= 1) q += __shfl_xor(q, m, 64);
    float rs = rsqrtf(q * (1.f / H) + 1e-5f);

    float2 w2 = ((const float2*)lnw)[lane];
    float2 b2 = ((const float2*)lnb)[lane];
    float2 o;
    o.x = dx * rs * w2.x + b2.x;
    o.y = dy * rs * w2.y + b2.y;
    *(float2*)&out[(size_t)n * H + c2] = o;
}

// ---------------------------------------------------------------------------
// Fallback path (R4): barrier-free fused GEMM with atomics + separate LN
// ---------------------------------------------------------------------------
__global__ __launch_bounds__(512, 2)
void fused_edge_kernel(const f16* __restrict__ nfh, const int* __restrict__ senders,
                       const int* __restrict__ receivers, const float* __restrict__ ef,
                       const float* __restrict__ b, const f16* __restrict__ wbuf,
                       float* __restrict__ out, int n_edges) {
    __shared__ __align__(16) f16 Wlds[NSRC * H * H];  // 96 KB
    const int t = threadIdx.x;
    {
        const int4* g = (const int4*)wbuf;
        int4* d = (int4*)Wlds;
#pragma unroll
        for (int i = 0; i < 12; ++i) d[i * 512 + t] = g[i * 512 + t];
    }
    __syncthreads();

    const int lane = t & 63;
    const int wid = t >> 6;
    const int l15 = lane & 15;
    const int lg = lane >> 4;

    float bias[8];
#pragma unroll
    for (int cf = 0; cf < 8; ++cf) bias[cf] = b[cf * 16 + l15];

    const int ntiles = (n_edges + 63) >> 6;
    const int nworkers = gridDim.x * 8;

    for (int tile = blockIdx.x * 8 + wid; tile < ntiles; tile += nworkers) {
        const int e0 = tile * 64;
        int sid[4], rid[4];
#pragma unroll
        for (int rf = 0; rf < 4; ++rf) {
            int e = e0 + rf * 16 + l15;
            if (e >= n_edges) e = n_edges - 1;
            sid[rf] = senders[e];
            rid[rf] = receivers[e];
        }
        f32x4 acc[4][8];
#pragma unroll
        for (int rf = 0; rf < 4; ++rf)
#pragma unroll
            for (int cf = 0; cf < 8; ++cf) acc[rf][cf] = (f32x4){0.f, 0.f, 0.f, 0.f};

#pragma unroll
        for (int src = 0; src < 2; ++src) {
#pragma unroll
            for (int ks = 0; ks < 4; ++ks) {
                f16x8 a[4];
#pragma unroll
                for (int rf = 0; rf < 4; ++rf) {
                    const int row = (src == 0) ? sid[rf] : rid[rf];
                    a[rf] = *(const f16x8*)(nfh + (size_t)row * H + ks * 32 + lg * 8);
                }
#pragma unroll
                for (int cf = 0; cf < 8; ++cf) {
                    const int c = cf * 16 + l15;
                    unsigned off = ((unsigned)(src * 32768 + c * 256 + (ks * 32 + lg * 8) * 2))
                                   ^ ((unsigned)((c & 7) << 4));
                    f16x8 bf = *(const f16x8*)((const char*)Wlds + off);
#pragma unroll
                    for (int rf = 0; rf < 4; ++rf)
                        acc[rf][cf] = __builtin_amdgcn_mfma_f32_16x16x32_f16(
                            a[rf], bf, acc[rf][cf], 0, 0, 0);
                }
            }
        }
#pragma unroll
        for (int ks = 0; ks < 4; ++ks) {
            f16x8 a[4];
#pragma unroll
            for (int rf = 0; rf < 4; ++rf) {
                int e = e0 + rf * 16 + l15;
                if (e >= n_edges) e = n_edges - 1;
                const float* p = ef + (size_t)e * H + ks * 32 + lg * 8;
                float4 v0 = *(const float4*)p;
                float4 v1 = *(const float4*)(p + 4);
                f16x8 h;
                h[0] = (f16)v0.x; h[1] = (f16)v0.y; h[2] = (f16)v0.z; h[3] = (f16)v0.w;
                h[4] = (f16)v1.x; h[5] = (f16)v1.y; h[6] = (f16)v1.z; h[7] = (f16)v1.w;
                a[rf] = h;
            }
#pragma unroll
            for (int cf = 0; cf < 8; ++cf) {
                const int c = cf * 16 + l15;
                unsigned off = ((unsigned)(2 * 32768 + c * 256 + (ks * 32 + lg * 8) * 2))
                               ^ ((unsigned)((c & 7) << 4));
                f16x8 bf = *(const f16x8*)((const char*)Wlds + off);
#pragma unroll
                for (int rf = 0; rf < 4; ++rf)
                    acc[rf][cf] = __builtin_amdgcn_mfma_f32_16x16x32_f16(
                        a[rf], bf, acc[rf][cf], 0, 0, 0);
            }
        }
#pragma unroll
        for (int rf = 0; rf < 4; ++rf) {
#pragma unroll
            for (int q = 0; q < 4; ++q) {
                const int e = e0 + rf * 16 + lg * 4 + q;
                if (e < n_edges) {
                    const int r = receivers[e];
                    float* dst = out + (size_t)r * H;
#pragma unroll
                    for (int cf = 0; cf < 8; ++cf) {
                        float m = fmaxf(acc[rf][cf][q] + bias[cf], 0.f);
                        atomicAdd(dst + cf * 16 + l15, m);
                    }
                }
            }
        }
    }
}

__global__ __launch_bounds__(256, 4)
void ln_kernel(const float* __restrict__ nf, const float* __restrict__ lnw,
               const float* __restrict__ lnb, float* __restrict__ out, int n_nodes) {
    const int wv = threadIdx.x >> 6;
    const int lane = threadIdx.x & 63;
    const int row = blockIdx.x * (blockDim.x >> 6) + wv;
    if (row >= n_nodes) return;
    float2 a = ((const float2*)(nf + (size_t)row * H))[lane];
    float2 g = ((float2*)(out + (size_t)row * H))[lane];
    float vx = a.x + g.x, vy = a.y + g.y;
    float s = vx + vy;
#pragma unroll
    for (int m = 32; m; m >>= 1) s += __shfl_xor(s, m, 64);
    float mu = s * (1.f / H);
    float dx = vx - mu, dy = vy - mu;
    float q = dx * dx + dy * dy;
#pragma unroll
    for (int m = 32; m; m >>= 1) q += __shfl_xor(q, m, 64);
    float rs = rsqrtf(q * (1.f / H) + 1e-5f);
    float2 w2 = ((const float2*)lnw)[lane];
    float2 b2 = ((const float2*)lnb)[lane];
    float2 o;
    o.x = dx * rs * w2.x + b2.x;
    o.y = dy * rs * w2.y + b2.y;
    ((float2*)(out + (size_t)row * H))[lane] = o;
}

__global__ void naive_edge_kernel(const float* __restrict__ nf, const int* __restrict__ s,
                                  const int* __restrict__ r, const float* __restrict__ ef,
                                  const float* __restrict__ W, const float* __restrict__ b,
                                  float* __restrict__ out, int n_edges) {
    int e = blockIdx.x * 2 + (threadIdx.x >> 7);
    int c = threadIdx.x & 127;
    if (e >= n_edges) return;
    int se = s[e], re = r[e];
    float acc = b[c];
    for (int k = 0; k < H; ++k) {
        acc += nf[(size_t)se * H + k] * W[(size_t)k * H + c];
        acc += nf[(size_t)re * H + k] * W[(size_t)(H + k) * H + c];
        acc += ef[(size_t)e * H + k] * W[(size_t)(2 * H + k) * H + c];
    }
    atomicAdd(&out[(size_t)re * H + c], fmaxf(acc, 0.f));
}

// ---------------------------------------------------------------------------
extern "C" void kernel_launch(void* const* d_in, const int* in_sizes, int n_in,
                              void* d_out, int out_size, void* d_ws, size_t ws_size,
                              hipStream_t stream) {
    const float* nf        = (const float*)d_in[0];
    const int*   senders   = (const int*)d_in[1];
    const int*   receivers = (const int*)d_in[2];
    const float* ef        = (const float*)d_in[3];
    const float* W         = (const float*)d_in[4];
    const float* b         = (const float*)d_in[5];
    const float* lnw       = (const float*)d_in[6];
    const float* lnb       = (const float*)d_in[7];
    float* out = (float*)d_out;

    const int n_nodes = in_sizes[0] / H;  // 50000
    const int n_edges = in_sizes[1];      // 800000
    const int nfelem = n_nodes * H;

    // ws carve-out (256B aligned)
    size_t o = 0;
    auto carve = [&](size_t bytes) { size_t r = o; o += (bytes + 255) & ~(size_t)255; return r; };
    const size_t o_wbuf   = carve((size_t)NSRC * H * H * sizeof(f16));   // 96 KB
    const size_t o_nfh    = carve((size_t)nfelem * sizeof(f16));         // 12.8 MB (fallback only)
    const size_t o_cnt    = carve((size_t)n_nodes * 4);
    const size_t o_rowptr = carve((size_t)(n_nodes + 1) * 4);
    const size_t o_cursor = carve((size_t)n_nodes * 4);
    const size_t o_spos   = carve((size_t)n_edges * 4);
    const size_t o_ssend  = carve((size_t)n_edges * 4);
    const size_t o_ps     = carve((size_t)nfelem * sizeof(f16));         // 12.8 MB
    const size_t o_pr     = carve((size_t)nfelem * sizeof(float));       // 25.6 MB
    const size_t o_me     = carve((size_t)n_edges * H * sizeof(f16));    // 204.8 MB
    const size_t need_full = o;

    char* ws = (char*)d_ws;
    f16* wbuf = (f16*)(ws + o_wbuf);
    f16* nfh  = (f16*)(ws + o_nfh);

    if (ws_size >= need_full) {
        int* cnt    = (int*)(ws + o_cnt);
        int* rowptr = (int*)(ws + o_rowptr);
        int* cursor = (int*)(ws + o_cursor);
        int* spos   = (int*)(ws + o_spos);
        int* ssend  = (int*)(ws + o_ssend);
        f16* PS     = (f16*)(ws + o_ps);
        float* PR   = (float*)(ws + o_pr);
        f16* ME     = (f16*)(ws + o_me);

        zero_kernel<<<(n_nodes + 255) / 256, 256, 0, stream>>>(cnt, n_nodes);
        prep_w_kernel<<<(NSRC * H * H + 255) / 256, 256, 0, stream>>>(W, wbuf);
        hist_kernel<<<(n_edges + 255) / 256, 256, 0, stream>>>(receivers, cnt, n_edges);
        scan_kernel<<<1, 1024, 0, stream>>>(cnt, rowptr, cursor, n_nodes);
        scatter_kernel<<<(n_edges + 255) / 256, 256, 0, stream>>>(
            senders, receivers, cursor, spos, ssend, n_edges);

        const int ntile_n = (n_nodes + 63) / 64;
        node_proj_kernel<<<(ntile_n + 3) / 4, 256, 0, stream>>>(nf, b, wbuf, PS, PR, n_nodes);
        const int ntile_e = (n_edges + 63) / 64;
        edge_gemm_kernel<<<(ntile_e + 3) / 4, 256, 0, stream>>>(ef, spos, wbuf, ME, n_edges);
        aggregate_ln_kernel<<<(n_nodes + 3) / 4, 256, 0, stream>>>(
            nf, PS, PR, ME, rowptr, ssend, lnw, lnb, out, n_nodes);
    } else if (ws_size >= o_cnt) {  // enough for wbuf + nfh: R4 fallback
        hipMemsetAsync(d_out, 0, (size_t)nfelem * sizeof(float), stream);
        prep_w_kernel<<<(NSRC * H * H + 255) / 256, 256, 0, stream>>>(W, wbuf);
        prep_nf_kernel<<<(nfelem / 4 + 255) / 256, 256, 0, stream>>>(nf, nfh, nfelem);
        fused_edge_kernel<<<512, 512, 0, stream>>>(nfh, senders, receivers, ef, b,
                                                   wbuf, out, n_edges);
        ln_kernel<<<(n_nodes + 3) / 4, 256, 0, stream>>>(nf, lnw, lnb, out, n_nodes);
    } else {
        hipMemsetAsync(d_out, 0, (size_t)nfelem * sizeof(float), stream);
        naive_edge_kernel<<<(n_edges + 1) / 2, 256, 0, stream>>>(
            nf, senders, receivers, ef, W, b, out, n_edges);
        ln_kernel<<<(n_nodes + 3) / 4, 256, 0, stream>>>(nf, lnw, lnb, out, n_nodes);
    }
}